// Round 7
// baseline (2045.213 us; speedup 1.0000x reference)
//
#include <hip/hip_runtime.h>
#include <hip/hip_bf16.h>

// MeshGraphNet forward, MI355X round 7: weight-stationary persistent MFMA,
// now at 2 waves/SIMD. r6 was 1 wave/SIMD (4-wave block + 128KB LDS -> 1
// block/CU) => zero latency hiding, all pipes <17%. r7: 512-thread blocks,
// 8 waves x 16 rows (tile=128 rows), LDS exactly 128KB, launch_bounds(512,2)
// to cap VGPR at 256. Coalesced e/xb stores staged through the free h-LDS.

#define NN 50000
#define EE 300000

typedef unsigned int u32;
typedef unsigned short u16;
typedef __attribute__((ext_vector_type(8))) short bf16x8;
typedef __attribute__((ext_vector_type(4))) float f32x4;

__device__ __forceinline__ float bf2f(u16 v){ return __uint_as_float(((u32)v) << 16); }
__device__ __forceinline__ u16 f2bf(float f){
  u32 u = __float_as_uint(f);
  return (u16)((u + 0x7fffu + ((u >> 16) & 1u)) >> 16);
}
#define MFMA __builtin_amdgcn_mfma_f32_16x16x32_bf16

// ---------------- ingest: canonicalize all float inputs to fp32 -------------
struct CD { const void* src; float* dst; int n; };
struct IngestArgs { CD d[34]; };

__global__ __launch_bounds__(256)
void ingest_kernel(IngestArgs a, const u32* __restrict__ probe) {
  const bool isbf = (probe[0] == 0x3F803F80u);  // std_vec_x == ones
  const CD c = a.d[blockIdx.y];
  for (int i = blockIdx.x*256 + threadIdx.x; i < c.n; i += gridDim.x*256) {
    c.dst[i] = isbf ? bf2f(((const u16*)c.src)[i]) : ((const float*)c.src)[i];
  }
}

// ------- pack W[Ksrc][128] fp32 -> bf16 MFMA B-frag layout, K padded -------
struct PackDesc { const float* src; u16* dst; int K; int Ksrc; };
struct PackArgs { PackDesc d[20]; };

__global__ __launch_bounds__(256)
void pack_b_kernel(PackArgs pa) {
  const PackDesc p = pa.d[blockIdx.y];
  const int total = (p.K >> 5) * 512;
  for (int idx = blockIdx.x*256 + threadIdx.x; idx < total; idx += gridDim.x*256) {
    const int lane = idx & 63;
    const int tile = idx >> 6;
    const int nt = tile & 7, kt = tile >> 3;
    const int col = nt*16 + (lane & 15);
    const int k0  = kt*32 + (lane >> 4) * 8;
    u32 w4[4];
    #pragma unroll
    for (int jj = 0; jj < 4; ++jj) {
      const int ka = k0 + 2*jj, kb = k0 + 2*jj + 1;
      const u16 lo = (ka < p.Ksrc) ? f2bf(p.src[(size_t)ka * 128 + col]) : (u16)0;
      const u16 hi = (kb < p.Ksrc) ? f2bf(p.src[(size_t)kb * 128 + col]) : (u16)0;
      w4[jj] = (u32)lo | ((u32)hi << 16);
    }
    *(uint4*)(p.dst + (size_t)idx * 8) = make_uint4(w4[0], w4[1], w4[2], w4[3]);
  }
}

__global__ __launch_bounds__(256)
void zero_kernel(int4* __restrict__ p, int n4) {
  for (int i = blockIdx.x*256 + threadIdx.x; i < n4; i += gridDim.x*256)
    p[i] = make_int4(0, 0, 0, 0);
}

// ---------------- CSR build: counting sort by dst ---------------------------
__global__ __launch_bounds__(256)
void hist_kernel(const int* __restrict__ ei, int* __restrict__ deg) {
  for (int i = blockIdx.x*256 + threadIdx.x; i < EE; i += gridDim.x*256)
    atomicAdd(&deg[ei[EE + i]], 1);
}

__global__ __launch_bounds__(1024)
void scan_kernel(const int* __restrict__ deg, int* __restrict__ start,
                 int* __restrict__ cursor) {
  __shared__ int sums[1024];
  const int t = threadIdx.x;
  const int base = t * 49;
  int s = 0;
  for (int j = 0; j < 49; ++j) { const int i = base + j; if (i < NN) s += deg[i]; }
  sums[t] = s; __syncthreads();
  for (int off = 1; off < 1024; off <<= 1) {
    int v = (t >= off) ? sums[t - off] : 0;
    __syncthreads();
    sums[t] += v;
    __syncthreads();
  }
  int ex = (t == 0) ? 0 : sums[t - 1];
  for (int j = 0; j < 49; ++j) {
    const int i = base + j;
    if (i < NN) { start[i] = ex; cursor[i] = ex; ex += deg[i]; }
  }
  if (t == 1023) start[NN] = ex;
}

__global__ __launch_bounds__(256)
void scatter_kernel(const int* __restrict__ ei, int* __restrict__ cursor,
                    int* __restrict__ perm, int* __restrict__ src_p,
                    int* __restrict__ dst_p) {
  for (int i = blockIdx.x*256 + threadIdx.x; i < EE; i += gridDim.x*256) {
    const int c = ei[EE + i];
    const int pos = atomicAdd(&cursor[c], 1);
    perm[pos]  = i;
    src_p[pos] = ei[i];
    dst_p[pos] = c;
  }
}

// ---------------- encoders: MFMA, K padded to 32 ----------------------------
template<int KIN, int MODE>
__global__ __launch_bounds__(256)
void enc_mfma(const u16* __restrict__ w1pk, const float* __restrict__ b1,
              const u16* __restrict__ w2pk, const float* __restrict__ b2,
              const float* __restrict__ g,  const float* __restrict__ be,
              const float* __restrict__ raw, const float* __restrict__ mean,
              const float* __restrict__ stdv, const int* __restrict__ perm,
              float* __restrict__ x, u16* __restrict__ outb, int nrows)
{
  constexpr int STR = 296;
  __shared__ u16 As[64 * STR];
  const int lane  = threadIdx.x & 63;
  const int wv    = threadIdx.x >> 6;
  const int col_l = lane & 15;
  const int quad  = lane >> 4;
  const int m0    = wv * 16;
  const int r0    = blockIdx.x * 64;

  for (int t = lane; t < 256; t += 64)
    ((u32*)As)[(m0 + (t >> 4)) * 148 + (t & 15)] = 0u;
  for (int t = lane; t < 16 * KIN; t += 64) {
    const int r = t / KIN, k = t - r * KIN;
    int srow = min(r0 + m0 + r, nrows - 1);
    if constexpr (MODE == 1) srow = perm[srow];
    const float v = (raw[(size_t)srow * KIN + k] - mean[k]) / stdv[k];
    As[(m0 + r) * STR + k] = f2bf(v);
  }

  float b1v[8], b2v[8], gv[8], bev[8];
  #pragma unroll
  for (int nt = 0; nt < 8; ++nt) {
    b1v[nt] = b1[nt*16 + col_l]; b2v[nt] = b2[nt*16 + col_l];
    gv[nt]  = g [nt*16 + col_l]; bev[nt] = be[nt*16 + col_l];
  }

  const f32x4 zf = {0.f, 0.f, 0.f, 0.f};
  const bf16x8* bq1 = (const bf16x8*)w1pk;
  const bf16x8* bq2 = (const bf16x8*)w2pk;
  const u16* arow = As + (size_t)(m0 + col_l) * STR + quad * 8;

  f32x4 acc[8];
  #pragma unroll
  for (int nt = 0; nt < 8; ++nt) acc[nt] = zf;
  {
    const bf16x8 af = *(const bf16x8*)(arow);
    #pragma unroll
    for (int nt = 0; nt < 8; ++nt)
      acc[nt] = MFMA(af, bq1[nt*64 + lane], acc[nt], 0, 0, 0);
  }
  #pragma unroll
  for (int nt = 0; nt < 8; ++nt) {
    #pragma unroll
    for (int rg = 0; rg < 4; ++rg) {
      const float hv = fmaxf(acc[nt][rg] + b1v[nt], 0.f);
      As[(size_t)(m0 + quad*4 + rg) * STR + 32 + nt*16 + col_l] = f2bf(hv);
    }
  }
  f32x4 acc2[8];
  #pragma unroll
  for (int nt = 0; nt < 8; ++nt) acc2[nt] = zf;
  #pragma unroll
  for (int kt = 0; kt < 4; ++kt) {
    const bf16x8 af = *(const bf16x8*)(arow + 32 + kt * 32);
    #pragma unroll
    for (int nt = 0; nt < 8; ++nt)
      acc2[nt] = MFMA(af, bq2[(kt*8+nt)*64 + lane], acc2[nt], 0, 0, 0);
  }
  #pragma unroll
  for (int rg = 0; rg < 4; ++rg) {
    float v[8];
    float s1 = 0.f, s2 = 0.f;
    #pragma unroll
    for (int nt = 0; nt < 8; ++nt) {
      v[nt] = acc2[nt][rg] + b2v[nt];
      s1 += v[nt]; s2 += v[nt]*v[nt];
    }
    #pragma unroll
    for (int off = 1; off < 16; off <<= 1) {
      s1 += __shfl_xor(s1, off);
      s2 += __shfl_xor(s2, off);
    }
    const float mu   = s1 * (1.f/128.f);
    const float var  = s2 * (1.f/128.f) - mu*mu;
    const float rstd = rsqrtf(var + 1e-5f);
    const int rloc = m0 + quad*4 + rg;
    const int row  = r0 + rloc;
    #pragma unroll
    for (int nt = 0; nt < 8; ++nt) {
      const float y = (v[nt] - mu) * rstd * gv[nt] + bev[nt];
      As[(size_t)rloc * STR + 160 + nt*16 + col_l] = f2bf(y);
      if (MODE == 0 && row < nrows) x[(size_t)row*128 + nt*16 + col_l] = y;
    }
  }
  #pragma unroll
  for (int r = 0; r < 16; ++r) {
    const int row = r0 + m0 + r;
    if (row < nrows)
      ((u32*)(outb + (size_t)row * 128))[lane] =
          ((const u32*)(As + (size_t)(m0 + r) * STR + 160))[lane];
  }
}

// ---------------- edge update: weight-stationary, 8 waves x 16 rows ---------
// LDS: lw1 96KB | lh 32KB (128 rows x 256B, 16B-chunk XOR swizzle). = 128KB
__global__ __launch_bounds__(512, 2)
void edge_mfma(const u16* __restrict__ w1pk, const float* __restrict__ b1,
               const u16* __restrict__ w2pk, const float* __restrict__ b2,
               const float* __restrict__ g, const float* __restrict__ be,
               const u16* __restrict__ xb, u16* __restrict__ eb,
               const int* __restrict__ src_p, const int* __restrict__ dst_p)
{
  extern __shared__ u16 lds[];
  u16* lw1 = lds;            // 49152 u16
  u16* lh  = lds + 49152;    // 16384 u16

  const int lane = threadIdx.x & 63;
  const int wv   = threadIdx.x >> 6;     // 0..7
  const int m    = lane & 15;
  const int q    = lane >> 4;
  const int rbase = wv * 16;             // wave-private 16 rows of 128-row tile

  for (int i = threadIdx.x; i < 6144; i += 512)
    ((uint4*)lw1)[i] = ((const uint4*)w1pk)[i];

  bf16x8 w2r[32];
  #pragma unroll
  for (int f = 0; f < 32; ++f)
    w2r[f] = ((const bf16x8*)w2pk)[f*64 + lane];
  __syncthreads();

  const int ntiles = (EE + 127) >> 7;    // 2344
  bf16x8 A[12];

  auto loadA = [&](int t) {
    const int grow = min(t*128 + rbase + m, EE-1);
    const u16* p0 = xb + (size_t)src_p[grow] * 128 + q*8;
    const u16* p1 = xb + (size_t)dst_p[grow] * 128 + q*8;
    const u16* p2 = eb + (size_t)grow * 128 + q*8;
    #pragma unroll
    for (int kt = 0; kt < 4; ++kt) {
      A[kt]   = *(const bf16x8*)(p0 + kt*32);
      A[4+kt] = *(const bf16x8*)(p1 + kt*32);
      A[8+kt] = *(const bf16x8*)(p2 + kt*32);
    }
  };

  loadA(blockIdx.x);
  for (int t = blockIdx.x; t < ntiles; t += 256) {
    // ---- GEMM1: B from LDS, A in regs ----
    #pragma unroll
    for (int nt = 0; nt < 8; ++nt) {
      f32x4 c = {0.f,0.f,0.f,0.f};
      #pragma unroll
      for (int kt = 0; kt < 12; ++kt) {
        const bf16x8 bf = *(const bf16x8*)(lw1 + (size_t)(kt*8+nt)*512 + lane*8);
        c = MFMA(A[kt], bf, c, 0, 0, 0);
      }
      const float b1n = b1[nt*16 + m];
      #pragma unroll
      for (int rg = 0; rg < 4; ++rg) {
        const float hv = fmaxf(c[rg] + b1n, 0.f);
        const int row = rbase + q*4 + rg;
        const int col = nt*16 + m;
        lh[row*128 + (((col>>3) ^ (row&7))<<3) + (col&7)] = f2bf(hv);
      }
    }
    // ---- prefetch next tile's A (A regs free) ----
    const int tn = t + 256;
    if (tn < ntiles) loadA(tn);
    // ---- GEMM2: h from LDS, W2 in regs ----
    f32x4 acc2[8];
    #pragma unroll
    for (int nt = 0; nt < 8; ++nt) acc2[nt] = {0.f,0.f,0.f,0.f};
    #pragma unroll
    for (int kt2 = 0; kt2 < 4; ++kt2) {
      const int ra = rbase + m;
      const bf16x8 h0 = *(const bf16x8*)(lh + ra*128 + (((kt2*4+q) ^ (ra&7))<<3));
      #pragma unroll
      for (int nt = 0; nt < 8; ++nt)
        acc2[nt] = MFMA(h0, w2r[kt2*8+nt], acc2[nt], 0, 0, 0);
    }
    // ---- LN + residual -> lh (h region now free) ----
    #pragma unroll
    for (int rg = 0; rg < 4; ++rg) {
      const int rloc = q*4 + rg;
      const int grow = min(t*128 + rbase + rloc, EE-1);
      float v[8]; float s1 = 0.f, s2 = 0.f;
      #pragma unroll
      for (int nt = 0; nt < 8; ++nt) {
        v[nt] = acc2[nt][rg] + b2[nt*16 + m];
        s1 += v[nt]; s2 += v[nt]*v[nt];
      }
      #pragma unroll
      for (int off = 1; off < 16; off <<= 1) {
        s1 += __shfl_xor(s1, off);
        s2 += __shfl_xor(s2, off);
      }
      const float mu   = s1 * (1.f/128.f);
      const float rstd = rsqrtf(s2*(1.f/128.f) - mu*mu + 1e-5f);
      #pragma unroll
      for (int nt = 0; nt < 8; ++nt) {
        const float y  = (v[nt] - mu) * rstd * g[nt*16 + m] + be[nt*16 + m];
        const float eo = bf2f(eb[(size_t)grow*128 + nt*16 + m]);
        const int row = rbase + rloc;
        const int col = nt*16 + m;
        lh[row*128 + (((col>>3) ^ (row&7))<<3) + (col&7)] = f2bf(y + eo);
      }
    }
    // ---- coalesced e_perm row stores (de-swizzled u32 reads) ----
    #pragma unroll
    for (int r = 0; r < 16; ++r) {
      const int grow = t*128 + rbase + r;
      if (grow < EE) {
        const int ch = (lane >> 2) ^ (r & 7);
        ((u32*)(eb + (size_t)grow * 128))[lane] =
            *(const u32*)(lh + (rbase + r)*128 + (ch<<3) + 2*(lane & 3));
      }
    }
  }
}

// ---------------- node update: weight-stationary, 8 waves x 16 rows ---------
// LDS: lw1 64KB | lh 32KB | lag 32KB = 128KB
__global__ __launch_bounds__(512, 2)
void node_mfma(const u16* __restrict__ w1pk, const float* __restrict__ b1,
               const u16* __restrict__ w2pk, const float* __restrict__ b2,
               const float* __restrict__ g, const float* __restrict__ be,
               float* __restrict__ x, u16* __restrict__ xb,
               const u16* __restrict__ eb, const int* __restrict__ start)
{
  extern __shared__ u16 lds[];
  u16* lw1 = lds;            // 32768 u16
  u16* lh  = lds + 32768;    // 16384 u16
  u16* lag = lds + 49152;    // 16384 u16

  const int lane = threadIdx.x & 63;
  const int wv   = threadIdx.x >> 6;
  const int m    = lane & 15;
  const int q    = lane >> 4;
  const int rbase = wv * 16;

  for (int i = threadIdx.x; i < 4096; i += 512)
    ((uint4*)lw1)[i] = ((const uint4*)w1pk)[i];

  bf16x8 w2r[32];
  #pragma unroll
  for (int f = 0; f < 32; ++f)
    w2r[f] = ((const bf16x8*)w2pk)[f*64 + lane];
  __syncthreads();

  const int ntiles = (NN + 127) >> 7;    // 391
  for (int t = blockIdx.x; t < ntiles; t += 256) {
    const int gbase = t*128 + rbase;
    // ---- CSR aggregation into swizzled lag (wave-private rows) ----
    const int sv = start[min(gbase + (lane & 31), NN)];
    for (int r = 0; r < 16; ++r) {
      const int s0 = __shfl(sv, r), s1 = __shfl(sv, r + 1);
      float a0 = 0.f, a1 = 0.f;
      int j = s0;
      for (; j + 4 <= s1; j += 4) {
        const u32 q0 = ((const u32*)(eb + (size_t)(j  ) * 128))[lane];
        const u32 q1 = ((const u32*)(eb + (size_t)(j+1) * 128))[lane];
        const u32 q2 = ((const u32*)(eb + (size_t)(j+2) * 128))[lane];
        const u32 q3 = ((const u32*)(eb + (size_t)(j+3) * 128))[lane];
        a0 += bf2f((u16)q0) + bf2f((u16)q1) + bf2f((u16)q2) + bf2f((u16)q3);
        a1 += bf2f((u16)(q0>>16)) + bf2f((u16)(q1>>16)) + bf2f((u16)(q2>>16)) + bf2f((u16)(q3>>16));
      }
      for (; j < s1; ++j) {
        const u32 qq = ((const u32*)(eb + (size_t)j * 128))[lane];
        a0 += bf2f((u16)qq); a1 += bf2f((u16)(qq>>16));
      }
      const int lr = rbase + r;
      const int ch = (lane >> 2) ^ (r & 7);
      *(u32*)(lag + lr*128 + (ch<<3) + 2*(lane & 3)) =
          (u32)f2bf(a0) | ((u32)f2bf(a1) << 16);
    }
    // ---- A frags: xb from global, agg from LDS ----
    bf16x8 A[8];
    {
      const int grow = min(gbase + m, NN-1);
      const u16* p0 = xb + (size_t)grow * 128 + q*8;
      const int lr = rbase + m;
      #pragma unroll
      for (int kt = 0; kt < 4; ++kt) {
        A[kt]   = *(const bf16x8*)(p0 + kt*32);
        A[4+kt] = *(const bf16x8*)(lag + lr*128 + (((kt*4+q) ^ (m&7))<<3));
      }
    }
    // ---- GEMM1 ----
    #pragma unroll
    for (int nt = 0; nt < 8; ++nt) {
      f32x4 c = {0.f,0.f,0.f,0.f};
      #pragma unroll
      for (int kt = 0; kt < 8; ++kt) {
        const bf16x8 bf = *(const bf16x8*)(lw1 + (size_t)(kt*8+nt)*512 + lane*8);
        c = MFMA(A[kt], bf, c, 0, 0, 0);
      }
      const float b1n = b1[nt*16 + m];
      #pragma unroll
      for (int rg = 0; rg < 4; ++rg) {
        const float hv = fmaxf(c[rg] + b1n, 0.f);
        const int row = rbase + q*4 + rg;
        const int col = nt*16 + m;
        lh[row*128 + (((col>>3) ^ (row&7))<<3) + (col&7)] = f2bf(hv);
      }
    }
    // ---- GEMM2 ----
    f32x4 acc2[8];
    #pragma unroll
    for (int nt = 0; nt < 8; ++nt) acc2[nt] = {0.f,0.f,0.f,0.f};
    #pragma unroll
    for (int kt2 = 0; kt2 < 4; ++kt2) {
      const int ra = rbase + m;
      const bf16x8 h0 = *(const bf16x8*)(lh + ra*128 + (((kt2*4+q) ^ (ra&7))<<3));
      #pragma unroll
      for (int nt = 0; nt < 8; ++nt)
        acc2[nt] = MFMA(h0, w2r[kt2*8+nt], acc2[nt], 0, 0, 0);
    }
    // ---- LN + residual; x direct, xb staged via lh ----
    #pragma unroll
    for (int rg = 0; rg < 4; ++rg) {
      const int rloc = q*4 + rg;
      const int grow = t*128 + rbase + rloc;
      const int growc = min(grow, NN-1);
      float v[8]; float s1 = 0.f, s2 = 0.f;
      #pragma unroll
      for (int nt = 0; nt < 8; ++nt) {
        v[nt] = acc2[nt][rg] + b2[nt*16 + m];
        s1 += v[nt]; s2 += v[nt]*v[nt];
      }
      #pragma unroll
      for (int off = 1; off < 16; off <<= 1) {
        s1 += __shfl_xor(s1, off);
        s2 += __shfl_xor(s2, off);
      }
      const float mu   = s1 * (1.f/128.f);
      const float rstd = rsqrtf(s2*(1.f/128.f) - mu*mu + 1e-5f);
      #pragma unroll
      for (int nt = 0; nt < 8; ++nt) {
        const float y  = (v[nt] - mu) * rstd * g[nt*16 + m] + be[nt*16 + m];
        const float xn = y + x[(size_t)growc*128 + nt*16 + m];
        if (grow < NN) x[(size_t)grow*128 + nt*16 + m] = xn;
        const int row = rbase + rloc;
        const int col = nt*16 + m;
        lh[row*128 + (((col>>3) ^ (row&7))<<3) + (col&7)] = f2bf(xn);
      }
    }
    #pragma unroll
    for (int r = 0; r < 16; ++r) {
      const int grow = t*128 + rbase + r;
      if (grow < NN) {
        const int ch = (lane >> 2) ^ (r & 7);
        ((u32*)(xb + (size_t)grow * 128))[lane] =
            *(const u32*)(lh + (rbase + r)*128 + (ch<<3) + 2*(lane & 3));
      }
    }
  }
}

// ---------------- decoder ----------------------------------------------------
constexpr int TM  = 8;
constexpr int WPB = 2;

__global__ __launch_bounds__(WPB*64)
void decoder_kernel(const float* __restrict__ x,
                    const float* __restrict__ w1, const float* __restrict__ b1,
                    const float* __restrict__ w2, const float* __restrict__ b2,
                    void* __restrict__ out, const u32* __restrict__ probe,
                    int nrows)
{
  const bool isbf = (probe[0] == 0x3F803F80u);
  const int lane = threadIdx.x & 63;
  const int wv   = threadIdx.x >> 6;
  const int wgl  = blockIdx.x * WPB + wv;
  const int nw   = gridDim.x * WPB;
  extern __shared__ float smem[];
  float* in_s = smem + wv * (TM * 128);

  const float2* w1p = ((const float2*)w1) + lane;
  const float b1l = b1[2*lane], b1h = b1[2*lane+1];
  const float2 wA = ((const float2*)w2)[2*lane];
  const float2 wB = ((const float2*)w2)[2*lane+1];
  const float c0 = b2[0], c1 = b2[1];

  for (int r0 = wgl * TM; r0 < nrows; r0 += nw * TM) {
    const int rcnt = min(TM, nrows - r0);
    for (int t = lane; t < rcnt * 128; t += 64) {
      const int r = t >> 7, k = t & 127;
      in_s[r*128 + k] = x[(size_t)(r0+r)*128 + k];
    }
    float a0[TM], a1[TM];
    #pragma unroll
    for (int r=0;r<TM;++r){ a0[r]=0.f; a1[r]=0.f; }
    for (int k = 0; k < 128; k += 2) {
      const float2 wa = w1p[(k  )*64];
      const float2 wb = w1p[(k+1)*64];
      #pragma unroll
      for (int r=0;r<TM;++r){
        const float2 av = *(const float2*)(in_s + r*128 + k);
        a0[r] = fmaf(av.x, wa.x, a0[r]); a1[r] = fmaf(av.x, wa.y, a1[r]);
        a0[r] = fmaf(av.y, wb.x, a0[r]); a1[r] = fmaf(av.y, wb.y, a1[r]);
      }
    }
    for (int r = 0; r < rcnt; ++r) {
      const float h0 = fmaxf(a0[r] + b1l, 0.f);
      const float h1 = fmaxf(a1[r] + b1h, 0.f);
      float p0 = fmaf(h0, wA.x, h1 * wB.x);
      float p1 = fmaf(h0, wA.y, h1 * wB.y);
      #pragma unroll
      for (int off = 32; off; off >>= 1) {
        p0 += __shfl_xor(p0, off);
        p1 += __shfl_xor(p1, off);
      }
      if (lane == 0) {
        const float o0 = p0 + c0;
        const float o1 = p1 + c1;
        if (isbf) ((u32*)out)[r0 + r] = (u32)f2bf(o0) | ((u32)f2bf(o1) << 16);
        else      *(float2*)((float*)out + (size_t)(r0 + r)*2) = make_float2(o0, o1);
      }
    }
  }
}

extern "C" void kernel_launch(void* const* d_in, const int* in_sizes, int n_in,
                              void* d_out, int out_size, void* d_ws, size_t ws_size,
                              hipStream_t stream) {
  static const int src_idx[34] = {0,2,3,4,5,6,
    7,8,9,10,11,12, 13,14,15,16,17,18,
    19,20,21,22,23,24, 25,26,27,28,29,30, 31,32,33,34};
  static const int sz[34] = {550000,900000,11,11,3,3,
    1408,128,16384,128,128,128,
    384,128,16384,128,128,128,
    196608,512,65536,512,512,512,
    131072,512,65536,512,512,512,
    16384,128,256,2};

  IngestArgs ia;
  const float* cp[35] = {};
  float* w = (float*)d_ws;
  for (int j = 0; j < 34; ++j) {
    ia.d[j].src = d_in[src_idx[j]];
    ia.d[j].dst = w;
    ia.d[j].n   = sz[j];
    cp[src_idx[j]] = w;
    w += sz[j];
  }
  w = (float*)(((uintptr_t)w + 63) & ~(uintptr_t)63);
  float* x   = w;                              // fp32 [N,128]
  u16*   xb  = (u16*)(x + (size_t)NN*128);     // bf16 [N,128]
  u16*   e   = xb + (size_t)NN*128;            // bf16 [E,128], perm space
  u16*   pk  = e  + (size_t)EE*128;
  u16* pk_pe1 = pk;
  u16* pk_pe2 = pk_pe1 + (size_t)4*384*128;
  u16* pk_pn1 = pk_pe2 + (size_t)4*128*128;
  u16* pk_pn2 = pk_pn1 + (size_t)4*256*128;
  u16* pk_ne1 = pk_pn2 + (size_t)4*128*128;
  u16* pk_ne2 = pk_ne1 + (size_t)32*128;
  u16* pk_ee1 = pk_ne2 + (size_t)128*128;
  u16* pk_ee2 = pk_ee1 + (size_t)32*128;
  int* deg    = (int*)(pk_ee2 + (size_t)128*128);
  int* start  = deg + NN;
  int* cursor = start + NN + 1;
  int* perm   = cursor + NN;
  int* src_p  = perm + EE;
  int* dst_p  = src_p + EE;

  const u32* probe = (const u32*)d_in[4];
  const int* ei    = (const int*)d_in[1];

  hipFuncSetAttribute((const void*)edge_mfma,
                      hipFuncAttributeMaxDynamicSharedMemorySize, 131072);
  hipFuncSetAttribute((const void*)node_mfma,
                      hipFuncAttributeMaxDynamicSharedMemorySize, 131072);

  ingest_kernel<<<dim3(128, 34), 256, 0, stream>>>(ia, probe);

  PackArgs pa;
  for (int l = 0; l < 4; ++l) {
    pa.d[l*4+0] = { cp[19] + (size_t)l*384*128, pk_pe1 + (size_t)l*384*128, 384, 384 };
    pa.d[l*4+1] = { cp[21] + (size_t)l*128*128, pk_pe2 + (size_t)l*128*128, 128, 128 };
    pa.d[l*4+2] = { cp[25] + (size_t)l*256*128, pk_pn1 + (size_t)l*256*128, 256, 256 };
    pa.d[l*4+3] = { cp[27] + (size_t)l*128*128, pk_pn2 + (size_t)l*128*128, 128, 128 };
  }
  pa.d[16] = { cp[7],  pk_ne1,  32,  11 };
  pa.d[17] = { cp[9],  pk_ne2, 128, 128 };
  pa.d[18] = { cp[13], pk_ee1,  32,   3 };
  pa.d[19] = { cp[15], pk_ee2, 128, 128 };
  pack_b_kernel<<<dim3(24, 20), 256, 0, stream>>>(pa);

  zero_kernel<<<dim3(64), 256, 0, stream>>>((int4*)deg, NN/4);
  hist_kernel<<<dim3(512), 256, 0, stream>>>(ei, deg);
  scan_kernel<<<dim3(1), 1024, 0, stream>>>(deg, start, cursor);
  scatter_kernel<<<dim3(512), 256, 0, stream>>>(ei, cursor, perm, src_p, dst_p);

  enc_mfma<11, 0><<<dim3((NN + 63)/64), 256, 0, stream>>>(
      pk_ne1, cp[8], pk_ne2, cp[10], cp[11], cp[12],
      cp[0], cp[3], cp[4], nullptr, x, xb, NN);
  enc_mfma<3, 1><<<dim3((EE + 63)/64), 256, 0, stream>>>(
      pk_ee1, cp[14], pk_ee2, cp[16], cp[17], cp[18],
      cp[2], cp[5], cp[6], perm, nullptr, e, EE);

  for (int l = 0; l < 4; ++l) {
    edge_mfma<<<dim3(256), dim3(512), 131072, stream>>>(
        pk_pe1 + (size_t)l*384*128, cp[20] + l*128,
        pk_pe2 + (size_t)l*128*128, cp[22] + l*128,
        cp[23] + l*128, cp[24] + l*128,
        xb, e, src_p, dst_p);
    node_mfma<<<dim3(256), dim3(512), 131072, stream>>>(
        pk_pn1 + (size_t)l*256*128, cp[26] + l*128,
        pk_pn2 + (size_t)l*128*128, cp[28] + l*128,
        cp[29] + l*128, cp[30] + l*128,
        x, xb, e, start);
  }

  decoder_kernel<<<dim3((NN + TM*WPB - 1)/(TM*WPB)), dim3(WPB*64),
                   (size_t)(WPB*TM*128*4), stream>>>(
      x, cp[31], cp[32], cp[33], cp[34], d_out, probe, NN);
}

// Round 8
// 1149.272 us; speedup vs baseline: 1.7796x; 1.7796x over previous
//
#include <hip/hip_runtime.h>
#include <hip/hip_bf16.h>

// MeshGraphNet forward, MI355X round 8: weight-stationary, 8 waves, no spills.
// r7 post-mortem: w2r[32] = 128 VGPRs blew the (512,2) budget -> scratch
// spill/fill (+250MB memory traffic, FETCH 373MB). r8: W2 moved to LDS
// (edge LDS 96+32+32=160KB, node 64+32+32+32=160KB, 1 block/CU, 2 waves/SIMD),
// bias regs restored. VGPR ~150, no spills.

#define NN 50000
#define EE 300000

typedef unsigned int u32;
typedef unsigned short u16;
typedef __attribute__((ext_vector_type(8))) short bf16x8;
typedef __attribute__((ext_vector_type(4))) float f32x4;

__device__ __forceinline__ float bf2f(u16 v){ return __uint_as_float(((u32)v) << 16); }
__device__ __forceinline__ u16 f2bf(float f){
  u32 u = __float_as_uint(f);
  return (u16)((u + 0x7fffu + ((u >> 16) & 1u)) >> 16);
}
#define MFMA __builtin_amdgcn_mfma_f32_16x16x32_bf16

// ---------------- ingest: canonicalize all float inputs to fp32 -------------
struct CD { const void* src; float* dst; int n; };
struct IngestArgs { CD d[34]; };

__global__ __launch_bounds__(256)
void ingest_kernel(IngestArgs a, const u32* __restrict__ probe) {
  const bool isbf = (probe[0] == 0x3F803F80u);  // std_vec_x == ones
  const CD c = a.d[blockIdx.y];
  for (int i = blockIdx.x*256 + threadIdx.x; i < c.n; i += gridDim.x*256) {
    c.dst[i] = isbf ? bf2f(((const u16*)c.src)[i]) : ((const float*)c.src)[i];
  }
}

// ------- pack W[Ksrc][128] fp32 -> bf16 MFMA B-frag layout, K padded -------
struct PackDesc { const float* src; u16* dst; int K; int Ksrc; };
struct PackArgs { PackDesc d[20]; };

__global__ __launch_bounds__(256)
void pack_b_kernel(PackArgs pa) {
  const PackDesc p = pa.d[blockIdx.y];
  const int total = (p.K >> 5) * 512;
  for (int idx = blockIdx.x*256 + threadIdx.x; idx < total; idx += gridDim.x*256) {
    const int lane = idx & 63;
    const int tile = idx >> 6;
    const int nt = tile & 7, kt = tile >> 3;
    const int col = nt*16 + (lane & 15);
    const int k0  = kt*32 + (lane >> 4) * 8;
    u32 w4[4];
    #pragma unroll
    for (int jj = 0; jj < 4; ++jj) {
      const int ka = k0 + 2*jj, kb = k0 + 2*jj + 1;
      const u16 lo = (ka < p.Ksrc) ? f2bf(p.src[(size_t)ka * 128 + col]) : (u16)0;
      const u16 hi = (kb < p.Ksrc) ? f2bf(p.src[(size_t)kb * 128 + col]) : (u16)0;
      w4[jj] = (u32)lo | ((u32)hi << 16);
    }
    *(uint4*)(p.dst + (size_t)idx * 8) = make_uint4(w4[0], w4[1], w4[2], w4[3]);
  }
}

__global__ __launch_bounds__(256)
void zero_kernel(int4* __restrict__ p, int n4) {
  for (int i = blockIdx.x*256 + threadIdx.x; i < n4; i += gridDim.x*256)
    p[i] = make_int4(0, 0, 0, 0);
}

// ---------------- CSR build: counting sort by dst ---------------------------
__global__ __launch_bounds__(256)
void hist_kernel(const int* __restrict__ ei, int* __restrict__ deg) {
  for (int i = blockIdx.x*256 + threadIdx.x; i < EE; i += gridDim.x*256)
    atomicAdd(&deg[ei[EE + i]], 1);
}

__global__ __launch_bounds__(1024)
void scan_kernel(const int* __restrict__ deg, int* __restrict__ start,
                 int* __restrict__ cursor) {
  __shared__ int sums[1024];
  const int t = threadIdx.x;
  const int base = t * 49;
  int s = 0;
  for (int j = 0; j < 49; ++j) { const int i = base + j; if (i < NN) s += deg[i]; }
  sums[t] = s; __syncthreads();
  for (int off = 1; off < 1024; off <<= 1) {
    int v = (t >= off) ? sums[t - off] : 0;
    __syncthreads();
    sums[t] += v;
    __syncthreads();
  }
  int ex = (t == 0) ? 0 : sums[t - 1];
  for (int j = 0; j < 49; ++j) {
    const int i = base + j;
    if (i < NN) { start[i] = ex; cursor[i] = ex; ex += deg[i]; }
  }
  if (t == 1023) start[NN] = ex;
}

__global__ __launch_bounds__(256)
void scatter_kernel(const int* __restrict__ ei, int* __restrict__ cursor,
                    int* __restrict__ perm, int* __restrict__ src_p,
                    int* __restrict__ dst_p) {
  for (int i = blockIdx.x*256 + threadIdx.x; i < EE; i += gridDim.x*256) {
    const int c = ei[EE + i];
    const int pos = atomicAdd(&cursor[c], 1);
    perm[pos]  = i;
    src_p[pos] = ei[i];
    dst_p[pos] = c;
  }
}

// ---------------- encoders: MFMA, K padded to 32 ----------------------------
template<int KIN, int MODE>
__global__ __launch_bounds__(256)
void enc_mfma(const u16* __restrict__ w1pk, const float* __restrict__ b1,
              const u16* __restrict__ w2pk, const float* __restrict__ b2,
              const float* __restrict__ g,  const float* __restrict__ be,
              const float* __restrict__ raw, const float* __restrict__ mean,
              const float* __restrict__ stdv, const int* __restrict__ perm,
              float* __restrict__ x, u16* __restrict__ outb, int nrows)
{
  constexpr int STR = 296;
  __shared__ u16 As[64 * STR];
  const int lane  = threadIdx.x & 63;
  const int wv    = threadIdx.x >> 6;
  const int col_l = lane & 15;
  const int quad  = lane >> 4;
  const int m0    = wv * 16;
  const int r0    = blockIdx.x * 64;

  for (int t = lane; t < 256; t += 64)
    ((u32*)As)[(m0 + (t >> 4)) * 148 + (t & 15)] = 0u;
  for (int t = lane; t < 16 * KIN; t += 64) {
    const int r = t / KIN, k = t - r * KIN;
    int srow = min(r0 + m0 + r, nrows - 1);
    if constexpr (MODE == 1) srow = perm[srow];
    const float v = (raw[(size_t)srow * KIN + k] - mean[k]) / stdv[k];
    As[(m0 + r) * STR + k] = f2bf(v);
  }

  float b1v[8], b2v[8], gv[8], bev[8];
  #pragma unroll
  for (int nt = 0; nt < 8; ++nt) {
    b1v[nt] = b1[nt*16 + col_l]; b2v[nt] = b2[nt*16 + col_l];
    gv[nt]  = g [nt*16 + col_l]; bev[nt] = be[nt*16 + col_l];
  }

  const f32x4 zf = {0.f, 0.f, 0.f, 0.f};
  const bf16x8* bq1 = (const bf16x8*)w1pk;
  const bf16x8* bq2 = (const bf16x8*)w2pk;
  const u16* arow = As + (size_t)(m0 + col_l) * STR + quad * 8;

  f32x4 acc[8];
  #pragma unroll
  for (int nt = 0; nt < 8; ++nt) acc[nt] = zf;
  {
    const bf16x8 af = *(const bf16x8*)(arow);
    #pragma unroll
    for (int nt = 0; nt < 8; ++nt)
      acc[nt] = MFMA(af, bq1[nt*64 + lane], acc[nt], 0, 0, 0);
  }
  #pragma unroll
  for (int nt = 0; nt < 8; ++nt) {
    #pragma unroll
    for (int rg = 0; rg < 4; ++rg) {
      const float hv = fmaxf(acc[nt][rg] + b1v[nt], 0.f);
      As[(size_t)(m0 + quad*4 + rg) * STR + 32 + nt*16 + col_l] = f2bf(hv);
    }
  }
  f32x4 acc2[8];
  #pragma unroll
  for (int nt = 0; nt < 8; ++nt) acc2[nt] = zf;
  #pragma unroll
  for (int kt = 0; kt < 4; ++kt) {
    const bf16x8 af = *(const bf16x8*)(arow + 32 + kt * 32);
    #pragma unroll
    for (int nt = 0; nt < 8; ++nt)
      acc2[nt] = MFMA(af, bq2[(kt*8+nt)*64 + lane], acc2[nt], 0, 0, 0);
  }
  #pragma unroll
  for (int rg = 0; rg < 4; ++rg) {
    float v[8];
    float s1 = 0.f, s2 = 0.f;
    #pragma unroll
    for (int nt = 0; nt < 8; ++nt) {
      v[nt] = acc2[nt][rg] + b2v[nt];
      s1 += v[nt]; s2 += v[nt]*v[nt];
    }
    #pragma unroll
    for (int off = 1; off < 16; off <<= 1) {
      s1 += __shfl_xor(s1, off);
      s2 += __shfl_xor(s2, off);
    }
    const float mu   = s1 * (1.f/128.f);
    const float var  = s2 * (1.f/128.f) - mu*mu;
    const float rstd = rsqrtf(var + 1e-5f);
    const int rloc = m0 + quad*4 + rg;
    const int row  = r0 + rloc;
    #pragma unroll
    for (int nt = 0; nt < 8; ++nt) {
      const float y = (v[nt] - mu) * rstd * gv[nt] + bev[nt];
      As[(size_t)rloc * STR + 160 + nt*16 + col_l] = f2bf(y);
      if (MODE == 0 && row < nrows) x[(size_t)row*128 + nt*16 + col_l] = y;
    }
  }
  #pragma unroll
  for (int r = 0; r < 16; ++r) {
    const int row = r0 + m0 + r;
    if (row < nrows)
      ((u32*)(outb + (size_t)row * 128))[lane] =
          ((const u32*)(As + (size_t)(m0 + r) * STR + 160))[lane];
  }
}

// ---------------- edge update: weight-stationary, 8 waves x 16 rows ---------
// LDS: lw1 96KB | lw2 32KB | lh 32KB = 160KB (full CU, 1 block/CU, 2 w/SIMD)
__global__ __launch_bounds__(512, 2)
void edge_mfma(const u16* __restrict__ w1pk, const float* __restrict__ b1,
               const u16* __restrict__ w2pk, const float* __restrict__ b2,
               const float* __restrict__ g, const float* __restrict__ be,
               const u16* __restrict__ xb, u16* __restrict__ eb,
               const int* __restrict__ src_p, const int* __restrict__ dst_p)
{
  extern __shared__ u16 lds[];
  u16* lw1 = lds;            // 49152 u16
  u16* lw2 = lds + 49152;    // 16384 u16
  u16* lh  = lds + 65536;    // 16384 u16

  const int lane = threadIdx.x & 63;
  const int wv   = threadIdx.x >> 6;     // 0..7
  const int m    = lane & 15;
  const int q    = lane >> 4;
  const int rbase = wv * 16;

  for (int i = threadIdx.x; i < 6144; i += 512)
    ((uint4*)lw1)[i] = ((const uint4*)w1pk)[i];
  for (int i = threadIdx.x; i < 2048; i += 512)
    ((uint4*)lw2)[i] = ((const uint4*)w2pk)[i];

  float b1v[8], b2v[8], gv[8], bev[8];
  #pragma unroll
  for (int nt = 0; nt < 8; ++nt) {
    b1v[nt] = b1[nt*16 + m]; b2v[nt] = b2[nt*16 + m];
    gv[nt]  = g [nt*16 + m]; bev[nt] = be[nt*16 + m];
  }
  __syncthreads();

  const int ntiles = (EE + 127) >> 7;    // 2344
  bf16x8 A[12];

  auto loadA = [&](int t) {
    const int grow = min(t*128 + rbase + m, EE-1);
    const u16* p0 = xb + (size_t)src_p[grow] * 128 + q*8;
    const u16* p1 = xb + (size_t)dst_p[grow] * 128 + q*8;
    const u16* p2 = eb + (size_t)grow * 128 + q*8;
    #pragma unroll
    for (int kt = 0; kt < 4; ++kt) {
      A[kt]   = *(const bf16x8*)(p0 + kt*32);
      A[4+kt] = *(const bf16x8*)(p1 + kt*32);
      A[8+kt] = *(const bf16x8*)(p2 + kt*32);
    }
  };

  loadA(blockIdx.x);
  for (int t = blockIdx.x; t < ntiles; t += 256) {
    // ---- GEMM1: B from LDS, A in regs ----
    #pragma unroll
    for (int nt = 0; nt < 8; ++nt) {
      f32x4 c = {0.f,0.f,0.f,0.f};
      #pragma unroll
      for (int kt = 0; kt < 12; ++kt) {
        const bf16x8 bf = *(const bf16x8*)(lw1 + (size_t)(kt*8+nt)*512 + lane*8);
        c = MFMA(A[kt], bf, c, 0, 0, 0);
      }
      #pragma unroll
      for (int rg = 0; rg < 4; ++rg) {
        const float hv = fmaxf(c[rg] + b1v[nt], 0.f);
        const int row = rbase + q*4 + rg;
        const int col = nt*16 + m;
        lh[row*128 + (((col>>3) ^ (row&7))<<3) + (col&7)] = f2bf(hv);
      }
    }
    // ---- prefetch next tile's A (A regs free) ----
    const int tn = t + 256;
    if (tn < ntiles) loadA(tn);
    // ---- GEMM2: h from LDS, W2 from LDS ----
    f32x4 acc2[8];
    #pragma unroll
    for (int nt = 0; nt < 8; ++nt) acc2[nt] = {0.f,0.f,0.f,0.f};
    #pragma unroll
    for (int kt2 = 0; kt2 < 4; ++kt2) {
      const int ra = rbase + m;
      const bf16x8 h0 = *(const bf16x8*)(lh + ra*128 + (((kt2*4+q) ^ (ra&7))<<3));
      #pragma unroll
      for (int nt = 0; nt < 8; ++nt) {
        const bf16x8 bf = *(const bf16x8*)(lw2 + (size_t)(kt2*8+nt)*512 + lane*8);
        acc2[nt] = MFMA(h0, bf, acc2[nt], 0, 0, 0);
      }
    }
    // ---- LN + residual -> lh (h region now free) ----
    #pragma unroll
    for (int rg = 0; rg < 4; ++rg) {
      const int rloc = q*4 + rg;
      const int grow = min(t*128 + rbase + rloc, EE-1);
      float v[8]; float s1 = 0.f, s2 = 0.f;
      #pragma unroll
      for (int nt = 0; nt < 8; ++nt) {
        v[nt] = acc2[nt][rg] + b2v[nt];
        s1 += v[nt]; s2 += v[nt]*v[nt];
      }
      #pragma unroll
      for (int off = 1; off < 16; off <<= 1) {
        s1 += __shfl_xor(s1, off);
        s2 += __shfl_xor(s2, off);
      }
      const float mu   = s1 * (1.f/128.f);
      const float rstd = rsqrtf(s2*(1.f/128.f) - mu*mu + 1e-5f);
      #pragma unroll
      for (int nt = 0; nt < 8; ++nt) {
        const float y  = (v[nt] - mu) * rstd * gv[nt] + bev[nt];
        const float eo = bf2f(eb[(size_t)grow*128 + nt*16 + m]);
        const int row = rbase + rloc;
        const int col = nt*16 + m;
        lh[row*128 + (((col>>3) ^ (row&7))<<3) + (col&7)] = f2bf(y + eo);
      }
    }
    // ---- coalesced e_perm row stores (de-swizzled u32 reads) ----
    #pragma unroll
    for (int r = 0; r < 16; ++r) {
      const int grow = t*128 + rbase + r;
      if (grow < EE) {
        const int ch = (lane >> 2) ^ (r & 7);
        ((u32*)(eb + (size_t)grow * 128))[lane] =
            *(const u32*)(lh + (rbase + r)*128 + (ch<<3) + 2*(lane & 3));
      }
    }
  }
}

// ---------------- node update: weight-stationary, 8 waves x 16 rows ---------
// LDS: lw1 64KB | lw2 32KB | lh 32KB | lag 32KB = 160KB
__global__ __launch_bounds__(512, 2)
void node_mfma(const u16* __restrict__ w1pk, const float* __restrict__ b1,
               const u16* __restrict__ w2pk, const float* __restrict__ b2,
               const float* __restrict__ g, const float* __restrict__ be,
               float* __restrict__ x, u16* __restrict__ xb,
               const u16* __restrict__ eb, const int* __restrict__ start)
{
  extern __shared__ u16 lds[];
  u16* lw1 = lds;            // 32768 u16
  u16* lw2 = lds + 32768;    // 16384 u16
  u16* lh  = lds + 49152;    // 16384 u16
  u16* lag = lds + 65536;    // 16384 u16

  const int lane = threadIdx.x & 63;
  const int wv   = threadIdx.x >> 6;
  const int m    = lane & 15;
  const int q    = lane >> 4;
  const int rbase = wv * 16;

  for (int i = threadIdx.x; i < 4096; i += 512)
    ((uint4*)lw1)[i] = ((const uint4*)w1pk)[i];
  for (int i = threadIdx.x; i < 2048; i += 512)
    ((uint4*)lw2)[i] = ((const uint4*)w2pk)[i];

  float b1v[8], b2v[8], gv[8], bev[8];
  #pragma unroll
  for (int nt = 0; nt < 8; ++nt) {
    b1v[nt] = b1[nt*16 + m]; b2v[nt] = b2[nt*16 + m];
    gv[nt]  = g [nt*16 + m]; bev[nt] = be[nt*16 + m];
  }
  __syncthreads();

  const int ntiles = (NN + 127) >> 7;    // 391
  for (int t = blockIdx.x; t < ntiles; t += 256) {
    const int gbase = t*128 + rbase;
    // ---- CSR aggregation into swizzled lag (wave-private rows) ----
    const int sv = start[min(gbase + (lane & 31), NN)];
    for (int r = 0; r < 16; ++r) {
      const int s0 = __shfl(sv, r), s1 = __shfl(sv, r + 1);
      float a0 = 0.f, a1 = 0.f;
      int j = s0;
      for (; j + 4 <= s1; j += 4) {
        const u32 q0 = ((const u32*)(eb + (size_t)(j  ) * 128))[lane];
        const u32 q1 = ((const u32*)(eb + (size_t)(j+1) * 128))[lane];
        const u32 q2 = ((const u32*)(eb + (size_t)(j+2) * 128))[lane];
        const u32 q3 = ((const u32*)(eb + (size_t)(j+3) * 128))[lane];
        a0 += bf2f((u16)q0) + bf2f((u16)q1) + bf2f((u16)q2) + bf2f((u16)q3);
        a1 += bf2f((u16)(q0>>16)) + bf2f((u16)(q1>>16)) + bf2f((u16)(q2>>16)) + bf2f((u16)(q3>>16));
      }
      for (; j < s1; ++j) {
        const u32 qq = ((const u32*)(eb + (size_t)j * 128))[lane];
        a0 += bf2f((u16)qq); a1 += bf2f((u16)(qq>>16));
      }
      const int lr = rbase + r;
      const int ch = (lane >> 2) ^ (r & 7);
      *(u32*)(lag + lr*128 + (ch<<3) + 2*(lane & 3)) =
          (u32)f2bf(a0) | ((u32)f2bf(a1) << 16);
    }
    // ---- A frags: xb from global, agg from LDS ----
    bf16x8 A[8];
    {
      const int grow = min(gbase + m, NN-1);
      const u16* p0 = xb + (size_t)grow * 128 + q*8;
      const int lr = rbase + m;
      #pragma unroll
      for (int kt = 0; kt < 4; ++kt) {
        A[kt]   = *(const bf16x8*)(p0 + kt*32);
        A[4+kt] = *(const bf16x8*)(lag + lr*128 + (((kt*4+q) ^ (m&7))<<3));
      }
    }
    // ---- GEMM1 ----
    #pragma unroll
    for (int nt = 0; nt < 8; ++nt) {
      f32x4 c = {0.f,0.f,0.f,0.f};
      #pragma unroll
      for (int kt = 0; kt < 8; ++kt) {
        const bf16x8 bf = *(const bf16x8*)(lw1 + (size_t)(kt*8+nt)*512 + lane*8);
        c = MFMA(A[kt], bf, c, 0, 0, 0);
      }
      #pragma unroll
      for (int rg = 0; rg < 4; ++rg) {
        const float hv = fmaxf(c[rg] + b1v[nt], 0.f);
        const int row = rbase + q*4 + rg;
        const int col = nt*16 + m;
        lh[row*128 + (((col>>3) ^ (row&7))<<3) + (col&7)] = f2bf(hv);
      }
    }
    // ---- GEMM2 ----
    f32x4 acc2[8];
    #pragma unroll
    for (int nt = 0; nt < 8; ++nt) acc2[nt] = {0.f,0.f,0.f,0.f};
    #pragma unroll
    for (int kt2 = 0; kt2 < 4; ++kt2) {
      const int ra = rbase + m;
      const bf16x8 h0 = *(const bf16x8*)(lh + ra*128 + (((kt2*4+q) ^ (ra&7))<<3));
      #pragma unroll
      for (int nt = 0; nt < 8; ++nt) {
        const bf16x8 bf = *(const bf16x8*)(lw2 + (size_t)(kt2*8+nt)*512 + lane*8);
        acc2[nt] = MFMA(h0, bf, acc2[nt], 0, 0, 0);
      }
    }
    // ---- LN + residual; x direct, xb staged via lh ----
    #pragma unroll
    for (int rg = 0; rg < 4; ++rg) {
      const int rloc = q*4 + rg;
      const int grow = t*128 + rbase + rloc;
      const int growc = min(grow, NN-1);
      float v[8]; float s1 = 0.f, s2 = 0.f;
      #pragma unroll
      for (int nt = 0; nt < 8; ++nt) {
        v[nt] = acc2[nt][rg] + b2v[nt];
        s1 += v[nt]; s2 += v[nt]*v[nt];
      }
      #pragma unroll
      for (int off = 1; off < 16; off <<= 1) {
        s1 += __shfl_xor(s1, off);
        s2 += __shfl_xor(s2, off);
      }
      const float mu   = s1 * (1.f/128.f);
      const float rstd = rsqrtf(s2*(1.f/128.f) - mu*mu + 1e-5f);
      #pragma unroll
      for (int nt = 0; nt < 8; ++nt) {
        const float y  = (v[nt] - mu) * rstd * gv[nt] + bev[nt];
        const float xn = y + x[(size_t)growc*128 + nt*16 + m];
        if (grow < NN) x[(size_t)grow*128 + nt*16 + m] = xn;
        const int row = rbase + rloc;
        const int col = nt*16 + m;
        lh[row*128 + (((col>>3) ^ (row&7))<<3) + (col&7)] = f2bf(xn);
      }
    }
    #pragma unroll
    for (int r = 0; r < 16; ++r) {
      const int grow = t*128 + rbase + r;
      if (grow < NN) {
        const int ch = (lane >> 2) ^ (r & 7);
        ((u32*)(xb + (size_t)grow * 128))[lane] =
            *(const u32*)(lh + (rbase + r)*128 + (ch<<3) + 2*(lane & 3));
      }
    }
  }
}

// ---------------- decoder ----------------------------------------------------
constexpr int TM  = 8;
constexpr int WPB = 2;

__global__ __launch_bounds__(WPB*64)
void decoder_kernel(const float* __restrict__ x,
                    const float* __restrict__ w1, const float* __restrict__ b1,
                    const float* __restrict__ w2, const float* __restrict__ b2,
                    void* __restrict__ out, const u32* __restrict__ probe,
                    int nrows)
{
  const bool isbf = (probe[0] == 0x3F803F80u);
  const int lane = threadIdx.x & 63;
  const int wv   = threadIdx.x >> 6;
  const int wgl  = blockIdx.x * WPB + wv;
  const int nw   = gridDim.x * WPB;
  extern __shared__ float smem[];
  float* in_s = smem + wv * (TM * 128);

  const float2* w1p = ((const float2*)w1) + lane;
  const float b1l = b1[2*lane], b1h = b1[2*lane+1];
  const float2 wA = ((const float2*)w2)[2*lane];
  const float2 wB = ((const float2*)w2)[2*lane+1];
  const float c0 = b2[0], c1 = b2[1];

  for (int r0 = wgl * TM; r0 < nrows; r0 += nw * TM) {
    const int rcnt = min(TM, nrows - r0);
    for (int t = lane; t < rcnt * 128; t += 64) {
      const int r = t >> 7, k = t & 127;
      in_s[r*128 + k] = x[(size_t)(r0+r)*128 + k];
    }
    float a0[TM], a1[TM];
    #pragma unroll
    for (int r=0;r<TM;++r){ a0[r]=0.f; a1[r]=0.f; }
    for (int k = 0; k < 128; k += 2) {
      const float2 wa = w1p[(k  )*64];
      const float2 wb = w1p[(k+1)*64];
      #pragma unroll
      for (int r=0;r<TM;++r){
        const float2 av = *(const float2*)(in_s + r*128 + k);
        a0[r] = fmaf(av.x, wa.x, a0[r]); a1[r] = fmaf(av.x, wa.y, a1[r]);
        a0[r] = fmaf(av.y, wb.x, a0[r]); a1[r] = fmaf(av.y, wb.y, a1[r]);
      }
    }
    for (int r = 0; r < rcnt; ++r) {
      const float h0 = fmaxf(a0[r] + b1l, 0.f);
      const float h1 = fmaxf(a1[r] + b1h, 0.f);
      float p0 = fmaf(h0, wA.x, h1 * wB.x);
      float p1 = fmaf(h0, wA.y, h1 * wB.y);
      #pragma unroll
      for (int off = 32; off; off >>= 1) {
        p0 += __shfl_xor(p0, off);
        p1 += __shfl_xor(p1, off);
      }
      if (lane == 0) {
        const float o0 = p0 + c0;
        const float o1 = p1 + c1;
        if (isbf) ((u32*)out)[r0 + r] = (u32)f2bf(o0) | ((u32)f2bf(o1) << 16);
        else      *(float2*)((float*)out + (size_t)(r0 + r)*2) = make_float2(o0, o1);
      }
    }
  }
}

extern "C" void kernel_launch(void* const* d_in, const int* in_sizes, int n_in,
                              void* d_out, int out_size, void* d_ws, size_t ws_size,
                              hipStream_t stream) {
  static const int src_idx[34] = {0,2,3,4,5,6,
    7,8,9,10,11,12, 13,14,15,16,17,18,
    19,20,21,22,23,24, 25,26,27,28,29,30, 31,32,33,34};
  static const int sz[34] = {550000,900000,11,11,3,3,
    1408,128,16384,128,128,128,
    384,128,16384,128,128,128,
    196608,512,65536,512,512,512,
    131072,512,65536,512,512,512,
    16384,128,256,2};

  IngestArgs ia;
  const float* cp[35] = {};
  float* w = (float*)d_ws;
  for (int j = 0; j < 34; ++j) {
    ia.d[j].src = d_in[src_idx[j]];
    ia.d[j].dst = w;
    ia.d[j].n   = sz[j];
    cp[src_idx[j]] = w;
    w += sz[j];
  }
  w = (float*)(((uintptr_t)w + 63) & ~(uintptr_t)63);
  float* x   = w;                              // fp32 [N,128]
  u16*   xb  = (u16*)(x + (size_t)NN*128);     // bf16 [N,128]
  u16*   e   = xb + (size_t)NN*128;            // bf16 [E,128], perm space
  u16*   pk  = e  + (size_t)EE*128;
  u16* pk_pe1 = pk;
  u16* pk_pe2 = pk_pe1 + (size_t)4*384*128;
  u16* pk_pn1 = pk_pe2 + (size_t)4*128*128;
  u16* pk_pn2 = pk_pn1 + (size_t)4*256*128;
  u16* pk_ne1 = pk_pn2 + (size_t)4*128*128;
  u16* pk_ne2 = pk_ne1 + (size_t)32*128;
  u16* pk_ee1 = pk_ne2 + (size_t)128*128;
  u16* pk_ee2 = pk_ee1 + (size_t)32*128;
  int* deg    = (int*)(pk_ee2 + (size_t)128*128);
  int* start  = deg + NN;
  int* cursor = start + NN + 1;
  int* perm   = cursor + NN;
  int* src_p  = perm + EE;
  int* dst_p  = src_p + EE;

  const u32* probe = (const u32*)d_in[4];
  const int* ei    = (const int*)d_in[1];

  hipFuncSetAttribute((const void*)edge_mfma,
                      hipFuncAttributeMaxDynamicSharedMemorySize, 163840);
  hipFuncSetAttribute((const void*)node_mfma,
                      hipFuncAttributeMaxDynamicSharedMemorySize, 163840);

  ingest_kernel<<<dim3(128, 34), 256, 0, stream>>>(ia, probe);

  PackArgs pa;
  for (int l = 0; l < 4; ++l) {
    pa.d[l*4+0] = { cp[19] + (size_t)l*384*128, pk_pe1 + (size_t)l*384*128, 384, 384 };
    pa.d[l*4+1] = { cp[21] + (size_t)l*128*128, pk_pe2 + (size_t)l*128*128, 128, 128 };
    pa.d[l*4+2] = { cp[25] + (size_t)l*256*128, pk_pn1 + (size_t)l*256*128, 256, 256 };
    pa.d[l*4+3] = { cp[27] + (size_t)l*128*128, pk_pn2 + (size_t)l*128*128, 128, 128 };
  }
  pa.d[16] = { cp[7],  pk_ne1,  32,  11 };
  pa.d[17] = { cp[9],  pk_ne2, 128, 128 };
  pa.d[18] = { cp[13], pk_ee1,  32,   3 };
  pa.d[19] = { cp[15], pk_ee2, 128, 128 };
  pack_b_kernel<<<dim3(24, 20), 256, 0, stream>>>(pa);

  zero_kernel<<<dim3(64), 256, 0, stream>>>((int4*)deg, NN/4);
  hist_kernel<<<dim3(512), 256, 0, stream>>>(ei, deg);
  scan_kernel<<<dim3(1), 1024, 0, stream>>>(deg, start, cursor);
  scatter_kernel<<<dim3(512), 256, 0, stream>>>(ei, cursor, perm, src_p, dst_p);

  enc_mfma<11, 0><<<dim3((NN + 63)/64), 256, 0, stream>>>(
      pk_ne1, cp[8], pk_ne2, cp[10], cp[11], cp[12],
      cp[0], cp[3], cp[4], nullptr, x, xb, NN);
  enc_mfma<3, 1><<<dim3((EE + 63)/64), 256, 0, stream>>>(
      pk_ee1, cp[14], pk_ee2, cp[16], cp[17], cp[18],
      cp[2], cp[5], cp[6], perm, nullptr, e, EE);

  for (int l = 0; l < 4; ++l) {
    edge_mfma<<<dim3(256), dim3(512), 163840, stream>>>(
        pk_pe1 + (size_t)l*384*128, cp[20] + l*128,
        pk_pe2 + (size_t)l*128*128, cp[22] + l*128,
        cp[23] + l*128, cp[24] + l*128,
        xb, e, src_p, dst_p);
    node_mfma<<<dim3(256), dim3(512), 163840, stream>>>(
        pk_pn1 + (size_t)l*256*128, cp[26] + l*128,
        pk_pn2 + (size_t)l*128*128, cp[28] + l*128,
        cp[29] + l*128, cp[30] + l*128,
        x, xb, e, start);
  }

  decoder_kernel<<<dim3((NN + TM*WPB - 1)/(TM*WPB)), dim3(WPB*64),
                   (size_t)(WPB*TM*128*4), stream>>>(
      x, cp[31], cp[32], cp[33], cp[34], d_out, probe, NN);
}